// Round 3
// baseline (305.068 us; speedup 1.0000x reference)
//
#include <hip/hip_runtime.h>
#include <hip/hip_bf16.h>
#include <math.h>

// Problem constants
#define BATCH 64
#define SEQ   512
#define DIM   768
#define NW    256              // MAX_WORDS
#define NT    (BATCH * NW)     // 16384 tokens
#define KDIM  1536             // 2*DIM
#define HID   256              // router hidden
#define NL    7                // num labels

// GEMM tiling
#define BM  32
#define BK  64
#define BKP 72                 // padded LDS row stride (bf16) -> 144 B
#define NKT (KDIM / BK)        // 24

// Align chunking
#define WC  8                  // words per wave-task -> 4096 tasks

typedef __bf16 bf16_t;
typedef bf16_t bf16x4 __attribute__((ext_vector_type(4)));
typedef bf16_t bf16x8 __attribute__((ext_vector_type(8)));
typedef float  f32x4  __attribute__((ext_vector_type(4)));

// ---------------------------------------------------------------------------
// Kernel 1: convert router_w1 (1536 x 256 fp32) -> bf16 K-major tiles
// w1t[kc][n][kk].  Grid 192: block=(kc,kg) handles 8 k-rows; loads coalesced.
// ---------------------------------------------------------------------------
__global__ __launch_bounds__(256) void convert_w1_kernel(
    const float* __restrict__ w1, bf16_t* __restrict__ w1t)
{
    int kc = blockIdx.x >> 3;        // 0..23
    int kg = blockIdx.x & 7;         // 0..7
    int n  = threadIdx.x;            // 0..255
    bf16x8 v;
    #pragma unroll
    for (int j = 0; j < 8; j++)
        v[j] = (bf16_t)w1[(size_t)(kc * 64 + kg * 8 + j) * HID + n];
    *(bf16x8*)(w1t + (size_t)kc * (HID * BK) + n * BK + kg * 8) = v;
}

// ---------------------------------------------------------------------------
// Kernel 2: starts table. starts[t][b][w] = lower_bound(ids[b], w), w in [0,256];
// entry 256 = SEQ. Grid 128 = 2 tensors x 64 batches, 256 threads (one per w).
// ---------------------------------------------------------------------------
__global__ __launch_bounds__(256) void starts_kernel(
    const int* __restrict__ idh, const int* __restrict__ idr,
    int* __restrict__ starts)
{
    int blk = blockIdx.x;            // t*64 + b
    int t = blk >> 6;
    int b = blk & 63;
    const int* ids = (t ? idr : idh) + b * SEQ;
    int w = threadIdx.x;
    int lo = 0, hi = SEQ;
    while (lo < hi) {
        int m = (lo + hi) >> 1;
        if (ids[m] < w) lo = m + 1; else hi = m;
    }
    int* row = starts + blk * 257;
    row[w] = lo;
    if (w == 0) row[256] = SEQ;
}

// ---------------------------------------------------------------------------
// Kernel 3: segment-mean align, streaming. Wave-task = (b, tensor, 8-word
// chunk): subtoken range is contiguous; per-word bounds come from starts.
// Grid 1024 x 256 (4 independent waves/block, no barriers).
// ---------------------------------------------------------------------------
__global__ __launch_bounds__(256) void align_kernel(
    const float* __restrict__ hh, const float* __restrict__ hr,
    const int* __restrict__ starts, bf16_t* __restrict__ X)
{
    int tid  = threadIdx.x;
    int lane = tid & 63;
    int wv   = tid >> 6;
    int task = blockIdx.x * 4 + wv;       // 4096 tasks
    int b = task >> 6;                    // 64 tasks per batch row
    int t = (task >> 5) & 1;
    int c = task & 31;
    int w0 = c * WC;

    const int*   st    = starts + (t * 64 + b) * 257;
    const f32x4* base4 = (const f32x4*)((t ? hr : hh) + (size_t)b * SEQ * DIM);
    bf16_t*      dstb  = X + (size_t)b * NW * KDIM + t * DIM;

    int lo = st[w0];
    #pragma unroll 1
    for (int w = w0; w < w0 + WC; w++) {
        int hi = st[w + 1];
        bf16_t* xr = dstb + (size_t)w * KDIM;
        if (hi > lo) {
            f32x4 a0 = {0,0,0,0}, a1 = {0,0,0,0}, a2 = {0,0,0,0};
            for (int s = lo; s < hi; s++) {
                const f32x4* row = base4 + (size_t)s * (DIM / 4);
                a0 += row[lane];
                a1 += row[lane + 64];
                a2 += row[lane + 128];
            }
            float inv = 1.0f / (float)(hi - lo);
            bf16x4 o0, o1, o2;
            #pragma unroll
            for (int e = 0; e < 4; e++) {
                o0[e] = (bf16_t)(a0[e] * inv);
                o1[e] = (bf16_t)(a1[e] * inv);
                o2[e] = (bf16_t)(a2[e] * inv);
            }
            *(bf16x4*)(xr + (lane)       * 4) = o0;
            *(bf16x4*)(xr + (lane + 64)  * 4) = o1;
            *(bf16x4*)(xr + (lane + 128) * 4) = o2;
        } else {
            bf16x4 z = {};
            *(bf16x4*)(xr + (lane)       * 4) = z;
            *(bf16x4*)(xr + (lane + 64)  * 4) = z;
            *(bf16x4*)(xr + (lane + 128) * 4) = z;
        }
        lo = hi;
    }
}

// ---------------------------------------------------------------------------
// Kernel 4: router GEMM (bf16 MFMA) -> alpha only. Unchanged from R2.
// ---------------------------------------------------------------------------
__global__ __launch_bounds__(256) void gemm_alpha_kernel(
    const bf16_t* __restrict__ X, const bf16_t* __restrict__ w1t,
    const float* __restrict__ b1, const float* __restrict__ w2,
    const float* __restrict__ b2, float* __restrict__ out)
{
    __shared__ __align__(16) bf16_t Xs[BM][BKP];
    __shared__ __align__(16) bf16_t Ws[HID][BKP];
    __shared__ float alpha_acc[BM];

    int tid   = threadIdx.x;
    int lane  = tid & 63;
    int wv    = tid >> 6;
    int row16 = lane & 15;
    int quad  = lane >> 4;
    int tok0  = blockIdx.x * BM;

    f32x4 acc[2][4];
    #pragma unroll
    for (int mi = 0; mi < 2; mi++)
        #pragma unroll
        for (int ni = 0; ni < 4; ni++)
            acc[mi][ni] = (f32x4){0.f, 0.f, 0.f, 0.f};

    int xr = tid >> 3;
    int xc = tid & 7;

    for (int kc = 0; kc < NKT; kc++) {
        {
            const uint4* src = (const uint4*)(X + (size_t)(tok0 + xr) * KDIM + kc * BK + xc * 8);
            *(uint4*)(&Xs[xr][xc * 8]) = *src;
        }
        {
            const uint4* srcb = (const uint4*)(w1t + (size_t)kc * (HID * BK));
            #pragma unroll
            for (int i = 0; i < 8; i++) {
                int cidx = tid + i * 256;
                *(uint4*)(&Ws[cidx >> 3][(cidx & 7) * 8]) = srcb[cidx];
            }
        }
        __syncthreads();
        #pragma unroll
        for (int kk2 = 0; kk2 < 2; kk2++) {
            bf16x8 af[2], bfg[4];
            #pragma unroll
            for (int mi = 0; mi < 2; mi++)
                af[mi] = *(const bf16x8*)(&Xs[mi * 16 + row16][kk2 * 32 + quad * 8]);
            #pragma unroll
            for (int ni = 0; ni < 4; ni++)
                bfg[ni] = *(const bf16x8*)(&Ws[wv * 64 + ni * 16 + row16][kk2 * 32 + quad * 8]);
            #pragma unroll
            for (int mi = 0; mi < 2; mi++)
                #pragma unroll
                for (int ni = 0; ni < 4; ni++)
                    acc[mi][ni] = __builtin_amdgcn_mfma_f32_16x16x32_bf16(
                        af[mi], bfg[ni], acc[mi][ni], 0, 0, 0);
        }
        __syncthreads();
    }

    float w2v[4], b1v[4];
    #pragma unroll
    for (int ni = 0; ni < 4; ni++) {
        int col = wv * 64 + ni * 16 + row16;
        w2v[ni] = w2[col];
        b1v[ni] = b1[col];
    }
    if (tid < BM) alpha_acc[tid] = 0.f;
    __syncthreads();

    #pragma unroll
    for (int mi = 0; mi < 2; mi++) {
        #pragma unroll
        for (int r = 0; r < 4; r++) {
            float p = 0.f;
            #pragma unroll
            for (int ni = 0; ni < 4; ni++) {
                float v = acc[mi][ni][r] + b1v[ni];
                v = v > 0.f ? v : 0.f;
                p += v * w2v[ni];
            }
            p += __shfl_xor(p, 1);
            p += __shfl_xor(p, 2);
            p += __shfl_xor(p, 4);
            p += __shfl_xor(p, 8);
            if (row16 == 0)
                atomicAdd(&alpha_acc[mi * 16 + quad * 4 + r], p);
        }
    }
    __syncthreads();
    if (tid < BM) {
        float a = 1.f / (1.f + expf(-(alpha_acc[tid] + b2[0])));
        out[(size_t)NT * NL + tok0 + tid] = a;
    }
}

// ---------------------------------------------------------------------------
// Kernel 5: blend + head + l2. hw staged in LDS transposed [l][d] so the
// per-l reads are ds_read_b128 (bandwidth-only cost) instead of 64-line L1
// fan-out. Wave per token, grid NT/4.
// ---------------------------------------------------------------------------
__global__ __launch_bounds__(256) void blend_kernel(
    const bf16_t* __restrict__ X, const float* __restrict__ hw,
    const float* __restrict__ hb, float* __restrict__ out)
{
    __shared__ float hws[NL * DIM];       // 21504 B, transposed [l][d]
    int tid  = threadIdx.x;
    int lane = tid & 63;
    int wv   = tid >> 6;

    for (int i = tid; i < DIM * NL; i += 256) {
        int d = i / NL, l = i - d * NL;   // source is [d][l]
        hws[l * DIM + d] = hw[i];
    }
    __syncthreads();

    int tok = blockIdx.x * 4 + wv;
    const float* alpha = out + (size_t)NT * NL;
    float a = alpha[tok];
    const bf16_t* xrow = X + (size_t)tok * KDIM;

    float lg[NL] = {0.f, 0.f, 0.f, 0.f, 0.f, 0.f, 0.f};
    float l2 = 0.f;

    #pragma unroll
    for (int j = 0; j < 3; j++) {
        int d0 = (lane + 64 * j) * 4;
        bf16x4 hp = *(const bf16x4*)(xrow + d0);
        bf16x4 rp = *(const bf16x4*)(xrow + DIM + d0);
        float bl[4];
        #pragma unroll
        for (int e = 0; e < 4; e++) {
            float hhv = (float)hp[e];
            float hrv = (float)rp[e];
            bl[e] = a * hhv + (1.f - a) * hrv;
            float df = hhv - hrv;
            l2 += df * df;
        }
        #pragma unroll
        for (int l = 0; l < NL; l++) {
            f32x4 wv4 = *(const f32x4*)(&hws[l * DIM + d0]);
            lg[l] += bl[0] * wv4[0] + bl[1] * wv4[1] + bl[2] * wv4[2] + bl[3] * wv4[3];
        }
    }

    #pragma unroll
    for (int off = 1; off < 64; off <<= 1) {
        #pragma unroll
        for (int l = 0; l < NL; l++) lg[l] += __shfl_xor(lg[l], off);
        l2 += __shfl_xor(l2, off);
    }

    if (lane < NL)
        out[(size_t)tok * NL + lane] = lg[lane] + hb[lane];
    else if (lane == NL)
        out[(size_t)NT * NL + NT + tok] = sqrtf(l2);
}

// ---------------------------------------------------------------------------
extern "C" void kernel_launch(void* const* d_in, const int* in_sizes, int n_in,
                              void* d_out, int out_size, void* d_ws, size_t ws_size,
                              hipStream_t stream)
{
    const float* hh  = (const float*)d_in[0];
    const float* hr  = (const float*)d_in[1];
    const int*   idh = (const int*)d_in[2];
    const int*   idr = (const int*)d_in[3];
    const float* w1  = (const float*)d_in[5];
    const float* b1  = (const float*)d_in[6];
    const float* w2  = (const float*)d_in[7];
    const float* b2  = (const float*)d_in[8];
    const float* hw  = (const float*)d_in[9];
    const float* hb  = (const float*)d_in[10];
    float* out = (float*)d_out;

    bf16_t* X      = (bf16_t*)d_ws;                      // 50.33 MB
    bf16_t* w1t    = X + (size_t)NT * KDIM;              // 0.79 MB
    int*    starts = (int*)(w1t + (size_t)NKT * HID * BK); // 2*64*257*4 = 263 KB

    convert_w1_kernel<<<192, 256, 0, stream>>>(w1, w1t);
    starts_kernel<<<128, 256, 0, stream>>>(idh, idr, starts);
    align_kernel<<<1024, 256, 0, stream>>>(hh, hr, starts, X);
    gemm_alpha_kernel<<<NT / BM, 256, 0, stream>>>(X, w1t, b1, w2, b2, out);
    blend_kernel<<<NT / 4, 256, 0, stream>>>(X, hw, hb, out);
}